// Round 1
// baseline (285.852 us; speedup 1.0000x reference)
//
#include <hip/hip_runtime.h>
#include <hip/hip_bf16.h>
#include <cstdint>

typedef _Float16 f16;
typedef _Float16 f16x4 __attribute__((ext_vector_type(4)));
typedef _Float16 f16x8 __attribute__((ext_vector_type(8)));
typedef float f32x4 __attribute__((ext_vector_type(4)));

#define LNEG (-1e30f)

__device__ __forceinline__ f32x4 mfma16(f16x8 a, f16x8 b, f32x4 c){
    return __builtin_amdgcn_mfma_f32_16x16x32_f16(a, b, c, 0, 0, 0);
}

// ---------- f32 -> f16 convert, 4 elems/thread ----------
__global__ void cvt_f32_f16(const float* __restrict__ in, f16* __restrict__ out, int n4){
    int i = blockIdx.x * blockDim.x + threadIdx.x;
    if (i < n4){
        float4 v = ((const float4*)in)[i];
        f16x4 o = { (f16)v.x, (f16)v.y, (f16)v.z, (f16)v.w };
        *(f16x4*)&out[(size_t)i * 4] = o;
    }
}

// ---------- GEMM: out[m][n] = sum_k A[m][k] * W[n][k]  (x @ W.T) ----------
// 128x128 tile, BK=64, 4 waves (each 64x64), mfma 16x16x32 f16.
// LDS XOR-swizzled (colb ^= (row&7)<<4) -> <=2-way bank conflicts on ds_read_b128.
template<typename OutT>
__global__ __launch_bounds__(256) void gemm_xwt(
    const f16* __restrict__ A,   // M x K row-major
    const f16* __restrict__ W0,  // N x K row-major (weight), z-selected
    size_t wstride,
    OutT* __restrict__ out0,
    size_t ostride,
    int M, int N, int K)
{
    const int tid  = threadIdx.x;
    const int lane = tid & 63;
    const int w    = tid >> 6;
    const int wr   = w >> 1, wc = w & 1;
    const int m0   = blockIdx.y * 128;
    const int n0   = blockIdx.x * 128;
    const f16* Wz  = W0 + wstride * blockIdx.z;
    OutT* out      = out0 + ostride * blockIdx.z;

    __shared__ f16 At[128 * 64];
    __shared__ f16 Bt[128 * 64];

    f32x4 acc[4][4] = {};

    for (int k0 = 0; k0 < K; k0 += 64){
        // stage A and B tiles (reg-staged so LDS dest can be swizzled)
        #pragma unroll
        for (int j = 0; j < 4; ++j){
            int off  = (j * 256 + tid) * 16;          // byte offset in 16KB tile
            int row  = off >> 7;                      // 128 B per row (64 f16)
            int colb = off & 127;
            int swz  = row * 128 + (colb ^ ((row & 7) << 4));
            f16x8 av = *(const f16x8*)&A [(size_t)(m0 + row) * K + k0 + (colb >> 1)];
            *(f16x8*)((char*)At + swz) = av;
            f16x8 bv = *(const f16x8*)&Wz[(size_t)(n0 + row) * K + k0 + (colb >> 1)];
            *(f16x8*)((char*)Bt + swz) = bv;
        }
        __syncthreads();
        #pragma unroll
        for (int kk = 0; kk < 2; ++kk){
            f16x8 af[4], bf[4];
            #pragma unroll
            for (int mf = 0; mf < 4; ++mf){
                int row = wr * 64 + mf * 16 + (lane & 15);
                int cb  = (kk * 64 + 16 * (lane >> 4)) ^ ((row & 7) << 4);
                af[mf] = *(const f16x8*)((const char*)At + row * 128 + cb);
            }
            #pragma unroll
            for (int nf = 0; nf < 4; ++nf){
                int row = wc * 64 + nf * 16 + (lane & 15);
                int cb  = (kk * 64 + 16 * (lane >> 4)) ^ ((row & 7) << 4);
                bf[nf] = *(const f16x8*)((const char*)Bt + row * 128 + cb);
            }
            #pragma unroll
            for (int mf = 0; mf < 4; ++mf)
                #pragma unroll
                for (int nf = 0; nf < 4; ++nf)
                    acc[mf][nf] = mfma16(af[mf], bf[nf], acc[mf][nf]);
        }
        __syncthreads();
    }
    // epilogue: D layout col=lane&15, row=4*(lane>>4)+r (verified m89)
    #pragma unroll
    for (int mf = 0; mf < 4; ++mf){
        #pragma unroll
        for (int nf = 0; nf < 4; ++nf){
            #pragma unroll
            for (int r = 0; r < 4; ++r){
                int row = m0 + wr * 64 + mf * 16 + 4 * (lane >> 4) + r;
                int col = n0 + wc * 64 + nf * 16 + (lane & 15);
                out[(size_t)row * N + col] = (OutT)acc[mf][nf][r];
            }
        }
    }
}

// ---------- V (B,L,H,D) -> V^T (B*H, D=64, L=2048) ----------
__global__ __launch_bounds__(256) void transpose_v(const f16* __restrict__ v, f16* __restrict__ vt){
    const int t  = threadIdx.x;
    const int lt = blockIdx.x;         // l-tile (64 rows)
    const int bh = blockIdx.y;
    const int b  = bh >> 4, h = bh & 15;
    const int l0 = lt * 64;
    __shared__ f16 tile[64][72];
    #pragma unroll
    for (int r = 0; r < 2; ++r){
        int i  = t / 8 + 32 * r;       // local l
        int jb = t % 8;                // d block of 8
        f16x8 vv = *(const f16x8*)&v[(size_t)(b * 2048 + l0 + i) * 1024 + h * 64 + jb * 8];
        *(f16x8*)&tile[i][jb * 8] = vv;
    }
    __syncthreads();
    #pragma unroll
    for (int r = 0; r < 2; ++r){
        int d  = t / 8 + 32 * r;
        int lb = t % 8;
        f16x8 o;
        #pragma unroll
        for (int q2 = 0; q2 < 8; ++q2) o[q2] = tile[lb * 8 + q2][d];
        *(f16x8*)&vt[(size_t)(bh * 64 + d) * 2048 + l0 + lb * 8] = o;
    }
}

// ---------- fused causal flash attention ----------
// grid (L/128, B*H); 4 waves/block, 32 q-rows per wave, KBLK=64.
__global__ __launch_bounds__(256) void attn_fused(
    const f16* __restrict__ q,    // (B,L,H*D)
    const f16* __restrict__ k,    // (B,L,H*D)
    const f16* __restrict__ vt,   // (B*H, 64, 2048)
    const int* __restrict__ amask,// (B,L) int32
    f16* __restrict__ y)          // (B,L,H*D)
{
    const int tid  = threadIdx.x;
    const int lane = tid & 63;
    const int w    = tid >> 6;
    const int qt   = blockIdx.x;
    const int bh   = blockIdx.y;
    const int b    = bh >> 4, h = bh & 15;
    const int q0w  = qt * 128 + w * 32;

    __shared__ f16 plds[4][32][72];   // per-wave private P tile (padded: 2-way max)

    // hoist Q fragments: aq[mf][f] : rows q0w+mf*16+(l&15), d = f*32 + 8*(l>>4)..+7
    f16x8 aq[2][2];
    #pragma unroll
    for (int mf = 0; mf < 2; ++mf)
        #pragma unroll
        for (int f = 0; f < 2; ++f){
            int row = q0w + mf * 16 + (lane & 15);
            aq[mf][f] = *(const f16x8*)&q[(size_t)(b * 2048 + row) * 1024 + h * 64 + f * 32 + 8 * (lane >> 4)];
        }

    f32x4 acc_o[2][4] = {};
    float m_st[2][4], l_st[2][4];
    #pragma unroll
    for (int mf = 0; mf < 2; ++mf)
        #pragma unroll
        for (int r = 0; r < 4; ++r){ m_st[mf][r] = LNEG; l_st[mf][r] = 0.f; }

    const int nkt = ((q0w + 31) >> 6) + 1;   // causal: keys up to last row of this wave
    for (int kt = 0; kt < nkt; ++kt){
        const int k0 = kt * 64;
        // S = Q K^T  (16x16x32, B-frag = K rows read 16B contiguous)
        f32x4 acc_s[2][4] = {};
        #pragma unroll
        for (int f = 0; f < 2; ++f){
            #pragma unroll
            for (int nf = 0; nf < 4; ++nf){
                int krow = k0 + nf * 16 + (lane & 15);
                f16x8 bk = *(const f16x8*)&k[(size_t)(b * 2048 + krow) * 1024 + h * 64 + f * 32 + 8 * (lane >> 4)];
                acc_s[0][nf] = mfma16(aq[0][f], bk, acc_s[0][nf]);
                acc_s[1][nf] = mfma16(aq[1][f], bk, acc_s[1][nf]);
            }
        }
        // key-side token mask
        bool tok[4];
        #pragma unroll
        for (int nf = 0; nf < 4; ++nf){
            int key = k0 + nf * 16 + (lane & 15);
            tok[nf] = amask[b * 2048 + key] != 0;
        }
        // online softmax (rows spread over 16-lane groups; shfl_xor 1..8 reduce)
        #pragma unroll
        for (int mf = 0; mf < 2; ++mf){
            #pragma unroll
            for (int r = 0; r < 4; ++r){
                int row = q0w + mf * 16 + 4 * (lane >> 4) + r;
                float pv[4]; float tmax = LNEG;
                #pragma unroll
                for (int nf = 0; nf < 4; ++nf){
                    int key = k0 + nf * 16 + (lane & 15);
                    bool ok = (key <= row) && tok[nf];
                    float val = ok ? acc_s[mf][nf][r] * 0.125f : LNEG;
                    pv[nf] = val; tmax = fmaxf(tmax, val);
                }
                #pragma unroll
                for (int m2 = 1; m2 < 16; m2 <<= 1) tmax = fmaxf(tmax, __shfl_xor(tmax, m2));
                float newm = fmaxf(m_st[mf][r], tmax);
                float rs = 0.f;
                #pragma unroll
                for (int nf = 0; nf < 4; ++nf){
                    float p = (pv[nf] > -1e29f) ? __expf(pv[nf] - newm) : 0.f;
                    pv[nf] = p; rs += p;
                }
                #pragma unroll
                for (int m2 = 1; m2 < 16; m2 <<= 1) rs += __shfl_xor(rs, m2);
                float alpha = __expf(m_st[mf][r] - newm);
                m_st[mf][r] = newm;
                l_st[mf][r] = l_st[mf][r] * alpha + rs;
                #pragma unroll
                for (int nf = 0; nf < 4; ++nf) acc_o[mf][nf][r] *= alpha;
                int prow = mf * 16 + 4 * (lane >> 4) + r;
                #pragma unroll
                for (int nf = 0; nf < 4; ++nf)
                    plds[w][prow][nf * 16 + (lane & 15)] = (f16)pv[nf];
            }
        }
        __builtin_amdgcn_wave_barrier();   // per-wave LDS RAW ordering hint
        // O += P V  (A-frag = P from LDS, B-frag = V^T rows, 16B contiguous keys)
        #pragma unroll
        for (int f = 0; f < 2; ++f){
            f16x8 ap[2];
            #pragma unroll
            for (int mf = 0; mf < 2; ++mf)
                ap[mf] = *(const f16x8*)&plds[w][mf * 16 + (lane & 15)][f * 32 + 8 * (lane >> 4)];
            #pragma unroll
            for (int nf = 0; nf < 4; ++nf){
                int d = nf * 16 + (lane & 15);
                f16x8 bv = *(const f16x8*)&vt[(size_t)(bh * 64 + d) * 2048 + k0 + f * 32 + 8 * (lane >> 4)];
                acc_o[0][nf] = mfma16(ap[0], bv, acc_o[0][nf]);
                acc_o[1][nf] = mfma16(ap[1], bv, acc_o[1][nf]);
            }
        }
        __builtin_amdgcn_wave_barrier();   // before next iter overwrites P
    }
    // epilogue: normalize and store y (f16)
    #pragma unroll
    for (int mf = 0; mf < 2; ++mf){
        #pragma unroll
        for (int r = 0; r < 4; ++r){
            float inv = 1.f / l_st[mf][r];
            int row = q0w + mf * 16 + 4 * (lane >> 4) + r;
            #pragma unroll
            for (int nf = 0; nf < 4; ++nf){
                int d = nf * 16 + (lane & 15);
                y[(size_t)(b * 2048 + row) * 1024 + h * 64 + d] = (f16)(acc_o[mf][nf][r] * inv);
            }
        }
    }
}

extern "C" void kernel_launch(void* const* d_in, const int* in_sizes, int n_in,
                              void* d_out, int out_size, void* d_ws, size_t ws_size,
                              hipStream_t stream){
    const float* x  = (const float*)d_in[0];
    const int*   am = (const int*)d_in[1];   // jnp int64 demoted to int32 (x64 disabled)
    const float* Wq = (const float*)d_in[2];
    const float* Wk = (const float*)d_in[3];
    const float* Wv = (const float*)d_in[4];
    const float* Wp = (const float*)d_in[5];
    float* out = (float*)d_out;

    char* ws = (char*)d_ws;
    const size_t XE = (size_t)4096 * 1024;   // x / q / k / v / y element count
    const size_t WE = (size_t)1024 * 1024;   // weight element count

    f16* x16 = (f16*)(ws);                                   // XE
    f16* w16 = (f16*)(ws + XE * 2);                          // 4*WE
    f16* qkv = (f16*)(ws + XE * 2 + WE * 8);                 // 3*XE (q,k,v)
    f16* vt  = (f16*)(ws + XE * 2 + WE * 8 + XE * 6);        // XE
    f16* y16 = (f16*)(ws + XE * 2 + WE * 8 + XE * 8);        // XE

    cvt_f32_f16<<<(int)(XE / 4 / 256), 256, 0, stream>>>(x,  x16,          (int)(XE / 4));
    cvt_f32_f16<<<(int)(WE / 4 / 256), 256, 0, stream>>>(Wq, w16 + 0 * WE, (int)(WE / 4));
    cvt_f32_f16<<<(int)(WE / 4 / 256), 256, 0, stream>>>(Wk, w16 + 1 * WE, (int)(WE / 4));
    cvt_f32_f16<<<(int)(WE / 4 / 256), 256, 0, stream>>>(Wv, w16 + 2 * WE, (int)(WE / 4));
    cvt_f32_f16<<<(int)(WE / 4 / 256), 256, 0, stream>>>(Wp, w16 + 3 * WE, (int)(WE / 4));

    // fused QKV projection: z selects {Wq,Wk,Wv} and {q,k,v} outputs
    gemm_xwt<f16><<<dim3(8, 32, 3), 256, 0, stream>>>(x16, w16, WE, qkv, XE, 4096, 1024, 1024);

    transpose_v<<<dim3(32, 32), 256, 0, stream>>>(qkv + 2 * XE, vt);

    attn_fused<<<dim3(16, 32), 256, 0, stream>>>(qkv, qkv + XE, vt, am, y16);

    // output projection -> f32 d_out
    gemm_xwt<float><<<dim3(8, 32, 1), 256, 0, stream>>>(y16, w16 + 3 * WE, 0, out, 0, 4096, 1024, 1024);
}

// Round 2
// 132.869 us; speedup vs baseline: 2.1514x; 2.1514x over previous
//
#include <hip/hip_runtime.h>
#include <hip/hip_bf16.h>
#include <cstdint>

typedef _Float16 f16;
typedef _Float16 f16x4 __attribute__((ext_vector_type(4)));
typedef _Float16 f16x8 __attribute__((ext_vector_type(8)));
typedef float f32x4 __attribute__((ext_vector_type(4)));

#define LNEG (-1e30f)

__device__ __forceinline__ f32x4 mfma16(f16x8 a, f16x8 b, f32x4 c){
    return __builtin_amdgcn_mfma_f32_16x16x32_f16(a, b, c, 0, 0, 0);
}

// ---------- f32 -> f16 convert, 4 elems/thread ----------
__global__ void cvt_f32_f16(const float* __restrict__ in, f16* __restrict__ out, int n4){
    int i = blockIdx.x * blockDim.x + threadIdx.x;
    if (i < n4){
        float4 v = ((const float4*)in)[i];
        f16x4 o = { (f16)v.x, (f16)v.y, (f16)v.z, (f16)v.w };
        *(f16x4*)&out[(size_t)i * 4] = o;
    }
}

// ---------- GEMM: out[m][n] = sum_k A[m][k] * W[n][k]  (x @ W.T) ----------
template<typename OutT>
__global__ __launch_bounds__(256) void gemm_xwt(
    const f16* __restrict__ A, const f16* __restrict__ W0, size_t wstride,
    OutT* __restrict__ out0, size_t ostride, int M, int N, int K)
{
    const int tid  = threadIdx.x;
    const int lane = tid & 63;
    const int w    = tid >> 6;
    const int wr   = w >> 1, wc = w & 1;
    const int m0   = blockIdx.y * 128;
    const int n0   = blockIdx.x * 128;
    const f16* Wz  = W0 + wstride * blockIdx.z;
    OutT* out      = out0 + ostride * blockIdx.z;

    __shared__ f16 At[128 * 64];
    __shared__ f16 Bt[128 * 64];

    f32x4 acc[4][4] = {};

    for (int k0 = 0; k0 < K; k0 += 64){
        #pragma unroll
        for (int j = 0; j < 4; ++j){
            int off  = (j * 256 + tid) * 16;
            int row  = off >> 7;
            int colb = off & 127;
            int swz  = row * 128 + (colb ^ ((row & 7) << 4));
            f16x8 av = *(const f16x8*)&A [(size_t)(m0 + row) * K + k0 + (colb >> 1)];
            *(f16x8*)((char*)At + swz) = av;
            f16x8 bv = *(const f16x8*)&Wz[(size_t)(n0 + row) * K + k0 + (colb >> 1)];
            *(f16x8*)((char*)Bt + swz) = bv;
        }
        __syncthreads();
        #pragma unroll
        for (int kk = 0; kk < 2; ++kk){
            f16x8 af[4], bf[4];
            #pragma unroll
            for (int mf = 0; mf < 4; ++mf){
                int row = wr * 64 + mf * 16 + (lane & 15);
                int cb  = (kk * 64 + 16 * (lane >> 4)) ^ ((row & 7) << 4);
                af[mf] = *(const f16x8*)((const char*)At + row * 128 + cb);
            }
            #pragma unroll
            for (int nf = 0; nf < 4; ++nf){
                int row = wc * 64 + nf * 16 + (lane & 15);
                int cb  = (kk * 64 + 16 * (lane >> 4)) ^ ((row & 7) << 4);
                bf[nf] = *(const f16x8*)((const char*)Bt + row * 128 + cb);
            }
            #pragma unroll
            for (int mf = 0; mf < 4; ++mf)
                #pragma unroll
                for (int nf = 0; nf < 4; ++nf)
                    acc[mf][nf] = mfma16(af[mf], bf[nf], acc[mf][nf]);
        }
        __syncthreads();
    }
    #pragma unroll
    for (int mf = 0; mf < 4; ++mf)
        #pragma unroll
        for (int nf = 0; nf < 4; ++nf)
            #pragma unroll
            for (int r = 0; r < 4; ++r){
                int row = m0 + wr * 64 + mf * 16 + 4 * (lane >> 4) + r;
                int col = n0 + wc * 64 + nf * 16 + (lane & 15);
                out[(size_t)row * N + col] = (OutT)acc[mf][nf][r];
            }
}

// ---------- V (B,L,H,D) -> V^T (B*H, D=64, L=2048) ----------
__global__ __launch_bounds__(256) void transpose_v(const f16* __restrict__ v, f16* __restrict__ vt){
    const int t  = threadIdx.x;
    const int lt = blockIdx.x;
    const int bh = blockIdx.y;
    const int b  = bh >> 4, h = bh & 15;
    const int l0 = lt * 64;
    __shared__ f16 tile[64][72];
    #pragma unroll
    for (int r = 0; r < 2; ++r){
        int i  = t / 8 + 32 * r;
        int jb = t % 8;
        f16x8 vv = *(const f16x8*)&v[(size_t)(b * 2048 + l0 + i) * 1024 + h * 64 + jb * 8];
        *(f16x8*)&tile[i][jb * 8] = vv;
    }
    __syncthreads();
    #pragma unroll
    for (int r = 0; r < 2; ++r){
        int d  = t / 8 + 32 * r;
        int lb = t % 8;
        f16x8 o;
        #pragma unroll
        for (int q2 = 0; q2 < 8; ++q2) o[q2] = tile[lb * 8 + q2][d];
        *(f16x8*)&vt[(size_t)(bh * 64 + d) * 2048 + l0 + lb * 8] = o;
    }
}

// ---------- fused causal flash attention (swapped-QK^T, 16 q-rows/wave) ----------
// grid: 1024 blocks (32 qtiles x 32 bh, work-balance swizzled), 256 threads.
// Block covers 64 q-rows; wave w owns rows [qt*64+w*16, +16). K/V^T staged in
// LDS (double-buffered, XOR-swizzled); per-wave P tile in LDS.
__global__ __launch_bounds__(256, 4) void attn_fused(
    const f16* __restrict__ q, const f16* __restrict__ k,
    const f16* __restrict__ vt, const int* __restrict__ amask,
    f16* __restrict__ y)
{
    const int tid  = threadIdx.x;
    const int lane = tid & 63;
    const int w    = tid >> 6;
    const int g    = lane >> 4;       // 16-lane group 0..3
    const int qq   = lane & 15;       // lane-local q (softmax space) / col index

    // work-balance swizzle: co-resident blocks (ids == mod 256) get qt and 31-qt
    const int lin = blockIdx.x;
    const int jj = lin >> 8, ii = lin & 255;
    const int qt = (jj & 1) ? (31 - (ii & 31)) : (ii & 31);
    const int bh = (ii >> 5) | (jj << 3);
    const int b = bh >> 4, h = bh & 15;
    const int q0w = qt * 64 + w * 16;
    const int nkt = qt + 1;

    __shared__ char sK[2][64 * 128];   // K tile  [key][d], XOR-swizzled rows
    __shared__ char sV[2][64 * 128];   // V^T tile [d][key], XOR-swizzled rows
    __shared__ char sP[4][16 * 128];   // per-wave P [q][key], XOR-swizzled

    // staging geometry: thread handles chunks cid=2*tid, 2*tid+1 (16B each)
    const int srow = (tid * 2) >> 3;
    const int sc8a = (tid * 2) & 7, sc8b = sc8a + 1;
    const int swka = (sc8a * 16) ^ ((srow & 7) << 4);
    const int swkb = (sc8b * 16) ^ ((srow & 7) << 4);
    const f16* kbase  = k  + ((size_t)b * 2048) * 1024 + h * 64;
    const f16* vtbase = vt + (size_t)bh * 64 * 2048;

    // hoist Q fragments, pre-scaled by 1/sqrt(D)=0.125 (exact in f16)
    f16x8 aq[2];
    #pragma unroll
    for (int f = 0; f < 2; ++f){
        aq[f] = *(const f16x8*)&q[((size_t)(b * 2048 + q0w + qq)) * 1024 + h * 64 + f * 32 + 8 * g];
        #pragma unroll
        for (int j = 0; j < 8; ++j) aq[f][j] *= (f16)0.125f;
    }

    f32x4 acc_o[4] = {};      // O[q=4g+r][d=nf*16+qq]
    float m_ln = LNEG, l_ln = 0.f;   // softmax state for q-row q0w+qq

    // prologue: stage tile 0 into buffer 0
    {
        f16x8 ka  = *(const f16x8*)(kbase  + (size_t)srow * 1024 + sc8a * 8);
        f16x8 kb2 = *(const f16x8*)(kbase  + (size_t)srow * 1024 + sc8b * 8);
        f16x8 va  = *(const f16x8*)(vtbase + (size_t)srow * 2048 + sc8a * 8);
        f16x8 vb  = *(const f16x8*)(vtbase + (size_t)srow * 2048 + sc8b * 8);
        *(f16x8*)(sK[0] + srow * 128 + swka) = ka;
        *(f16x8*)(sK[0] + srow * 128 + swkb) = kb2;
        *(f16x8*)(sV[0] + srow * 128 + swka) = va;
        *(f16x8*)(sV[0] + srow * 128 + swkb) = vb;
    }
    __syncthreads();

    for (int kt = 0; kt < nkt; ++kt){
        const int cur = kt & 1;
        const int k0 = kt * 64;
        const bool pre = (kt + 1 < nkt);

        // T14 async-stage: issue next tile's global loads early
        f16x8 ka, kb2, va, vb;
        if (pre){
            const int nk0 = k0 + 64;
            ka  = *(const f16x8*)(kbase  + (size_t)(nk0 + srow) * 1024 + sc8a * 8);
            kb2 = *(const f16x8*)(kbase  + (size_t)(nk0 + srow) * 1024 + sc8b * 8);
            va  = *(const f16x8*)(vtbase + (size_t)srow * 2048 + nk0 + sc8a * 8);
            vb  = *(const f16x8*)(vtbase + (size_t)srow * 2048 + nk0 + sc8b * 8);
        }

        unsigned long long tokbits = __ballot(amask[b * 2048 + k0 + lane] != 0);
        const bool tokall = (tokbits == ~0ull);

        // QK^T swapped: acc_s[kf] holds S[key = kf*16+4g+r][q = qq]
        f32x4 acc_s[4] = {};
        #pragma unroll
        for (int kf = 0; kf < 4; ++kf){
            const int keyl = kf * 16 + qq;
            const char* kr = sK[cur] + keyl * 128;
            const int sw = (keyl & 7) << 4;
            #pragma unroll
            for (int f = 0; f < 2; ++f){
                f16x8 ak = *(const f16x8*)(kr + ((f * 64 + 16 * g) ^ sw));
                acc_s[kf] = mfma16(ak, aq[f], acc_s[kf]);
            }
        }

        // mask (only boundary tiles do per-value work)
        const bool fullt = (k0 + 63 <= q0w) && tokall;
        float sv[16];
        #pragma unroll
        for (int kf = 0; kf < 4; ++kf)
            #pragma unroll
            for (int r = 0; r < 4; ++r){
                float s = acc_s[kf][r];
                if (!fullt){
                    const int keyl = kf * 16 + 4 * g + r;
                    const bool ok = (k0 + keyl <= q0w + qq) && ((tokbits >> keyl) & 1);
                    s = ok ? s : LNEG;
                }
                sv[kf * 4 + r] = s;
            }

        // online softmax: 15 local max + 2 shfl (row lives in 4 lanes)
        float tmax = sv[0];
        #pragma unroll
        for (int i = 1; i < 16; ++i) tmax = fmaxf(tmax, sv[i]);
        tmax = fmaxf(tmax, __shfl_xor(tmax, 16));
        tmax = fmaxf(tmax, __shfl_xor(tmax, 32));
        const bool skip = __all(tmax <= m_ln + 5.f);   // T13 defer-max
        float alpha = 1.f;
        if (!skip){
            const float newm = fmaxf(m_ln, tmax);
            alpha = __expf(m_ln - newm);
            m_ln = newm;
        }
        float rs = 0.f;
        float pr[16];
        #pragma unroll
        for (int i = 0; i < 16; ++i){ pr[i] = __expf(sv[i] - m_ln); rs += pr[i]; }
        rs += __shfl_xor(rs, 16);
        rs += __shfl_xor(rs, 32);
        l_ln = l_ln * alpha + rs;
        if (!skip){
            #pragma unroll
            for (int r = 0; r < 4; ++r){
                const float ar = __shfl(alpha, 4 * g + r);  // alpha for q-row 4g+r
                #pragma unroll
                for (int nf = 0; nf < 4; ++nf) acc_o[nf][r] *= ar;
            }
        }

        // write P: 4x ds_write_b64, swizzled
        char* pbase = sP[w] + qq * 128;
        const int swp = (qq & 7) << 4;
        #pragma unroll
        for (int kf = 0; kf < 4; ++kf){
            f16x4 pk = { (f16)pr[kf*4+0], (f16)pr[kf*4+1], (f16)pr[kf*4+2], (f16)pr[kf*4+3] };
            *(f16x4*)(pbase + ((kf * 32 + 8 * g) ^ swp)) = pk;
        }

        // PV: A = P (rows=q), B = V^T (cols=d)
        #pragma unroll
        for (int f = 0; f < 2; ++f){
            f16x8 ap = *(const f16x8*)(pbase + ((f * 64 + 16 * g) ^ swp));
            #pragma unroll
            for (int nf = 0; nf < 4; ++nf){
                const int d = nf * 16 + qq;
                f16x8 bv = *(const f16x8*)(sV[cur] + d * 128 + ((f * 64 + 16 * g) ^ ((d & 7) << 4)));
                acc_o[nf] = mfma16(ap, bv, acc_o[nf]);
            }
        }

        // late LDS write of prefetched tile
        if (pre){
            const int nb = cur ^ 1;
            *(f16x8*)(sK[nb] + srow * 128 + swka) = ka;
            *(f16x8*)(sK[nb] + srow * 128 + swkb) = kb2;
            *(f16x8*)(sV[nb] + srow * 128 + swka) = va;
            *(f16x8*)(sV[nb] + srow * 128 + swkb) = vb;
        }
        __syncthreads();
    }

    // epilogue: broadcast 1/l into D-space, store
    const float invl = 1.f / l_ln;
    #pragma unroll
    for (int r = 0; r < 4; ++r){
        const float ir = __shfl(invl, 4 * g + r);
        const int row = q0w + 4 * g + r;
        #pragma unroll
        for (int nf = 0; nf < 4; ++nf)
            y[((size_t)(b * 2048 + row)) * 1024 + h * 64 + nf * 16 + qq] = (f16)(acc_o[nf][r] * ir);
    }
}

extern "C" void kernel_launch(void* const* d_in, const int* in_sizes, int n_in,
                              void* d_out, int out_size, void* d_ws, size_t ws_size,
                              hipStream_t stream){
    const float* x  = (const float*)d_in[0];
    const int*   am = (const int*)d_in[1];
    const float* Wq = (const float*)d_in[2];
    const float* Wk = (const float*)d_in[3];
    const float* Wv = (const float*)d_in[4];
    const float* Wp = (const float*)d_in[5];
    float* out = (float*)d_out;

    char* ws = (char*)d_ws;
    const size_t XE = (size_t)4096 * 1024;
    const size_t WE = (size_t)1024 * 1024;

    f16* x16 = (f16*)(ws);
    f16* w16 = (f16*)(ws + XE * 2);
    f16* qkv = (f16*)(ws + XE * 2 + WE * 8);
    f16* vt  = (f16*)(ws + XE * 2 + WE * 8 + XE * 6);
    f16* y16 = (f16*)(ws + XE * 2 + WE * 8 + XE * 8);

    cvt_f32_f16<<<(int)(XE / 4 / 256), 256, 0, stream>>>(x,  x16,          (int)(XE / 4));
    cvt_f32_f16<<<(int)(WE / 4 / 256), 256, 0, stream>>>(Wq, w16 + 0 * WE, (int)(WE / 4));
    cvt_f32_f16<<<(int)(WE / 4 / 256), 256, 0, stream>>>(Wk, w16 + 1 * WE, (int)(WE / 4));
    cvt_f32_f16<<<(int)(WE / 4 / 256), 256, 0, stream>>>(Wv, w16 + 2 * WE, (int)(WE / 4));
    cvt_f32_f16<<<(int)(WE / 4 / 256), 256, 0, stream>>>(Wp, w16 + 3 * WE, (int)(WE / 4));

    gemm_xwt<f16><<<dim3(8, 32, 3), 256, 0, stream>>>(x16, w16, WE, qkv, XE, 4096, 1024, 1024);

    transpose_v<<<dim3(32, 32), 256, 0, stream>>>(qkv + 2 * XE, vt);

    attn_fused<<<dim3(1024), 256, 0, stream>>>(qkv, qkv + XE, vt, am, y16);

    gemm_xwt<float><<<dim3(8, 32, 1), 256, 0, stream>>>(y16, w16 + 3 * WE, 0, out, 0, 4096, 1024, 1024);
}